// Round 6
// baseline (672.882 us; speedup 1.0000x reference)
//
#include <hip/hip_runtime.h>
#include <stdint.h>

#define NP 8192           // particles
#define NC 8192           // channels
#define NS_E 6144         // samples materialized via E in k_fused (rows 0..6143)
#define NS_D 2048         // samples computed directly in k_race (6144..8191)

__host__ __device__ inline uint32_t rotl32(uint32_t x, int r) {
  return __builtin_rotateleft32(x, (unsigned)r);   // lowers to v_alignbit_b32 (verified R4)
}

// JAX threefry2x32: 20 rounds, key schedule injection every 4 rounds.
__host__ __device__ inline void threefry2x32(uint32_t k0, uint32_t k1,
                                             uint32_t x0, uint32_t x1,
                                             uint32_t& o0, uint32_t& o1) {
  uint32_t ks2 = k0 ^ k1 ^ 0x1BD11BDAu;
  x0 += k0; x1 += k1;
#define TF_R(r) { x0 += x1; x1 = rotl32(x1, (r)); x1 ^= x0; }
  TF_R(13) TF_R(15) TF_R(26) TF_R(6)   x0 += k1;  x1 += ks2 + 1u;
  TF_R(17) TF_R(29) TF_R(16) TF_R(24)  x0 += ks2; x1 += k0 + 2u;
  TF_R(13) TF_R(15) TF_R(26) TF_R(6)   x0 += k0;  x1 += k1 + 3u;
  TF_R(17) TF_R(29) TF_R(16) TF_R(24)  x0 += k1;  x1 += ks2 + 4u;
  TF_R(13) TF_R(15) TF_R(26) TF_R(6)   x0 += ks2; x1 += k0 + 5u;
#undef TF_R
  o0 = x0; o1 = x1;
}

// partitionable threefry random_bits, 32-bit: counter=(0,i), bits = o0 ^ o1
__device__ inline uint32_t tf_bits(uint32_t k0, uint32_t k1, uint32_t i) {
  uint32_t o0, o1;
  threefry2x32(k0, k1, 0u, i, o0, o1);
  return o0 ^ o1;
}

// uniform [0,1): (bits>>9)|0x3f800000 -> [1,2) -> -1
__device__ inline float u01(uint32_t bits) {
  return __uint_as_float((bits >> 9) | 0x3f800000u) - 1.0f;
}

// E = -log(uniform(tiny,1)); fl((-L)*w) == -fl(L*w) (IEEE sign symmetry), so
// E-then-multiply preserves the original fused -log(v)*winv argmin bit-for-bit.
__device__ inline float egen(uint32_t k0, uint32_t k1, uint32_t ctr) {
  const float TINY = 1.17549435e-38f;
  uint32_t bits = tf_bits(k0, k1, ctr);
  float v = fmaxf(u01(bits), TINY);
  return -__logf(v);
}

// XLA ErfInv32 (Giles) polynomial
__device__ inline float erfinvf_(float x) {
  float w = -log1pf(-x * x);
  float p;
  if (w < 5.0f) {
    w -= 2.5f;
    p = 2.81022636e-08f;
    p = fmaf(p, w, 3.43273939e-07f);
    p = fmaf(p, w, -3.5233877e-06f);
    p = fmaf(p, w, -4.39150654e-06f);
    p = fmaf(p, w, 0.00021858087f);
    p = fmaf(p, w, -0.00125372503f);
    p = fmaf(p, w, -0.00417768164f);
    p = fmaf(p, w, 0.246640727f);
    p = fmaf(p, w, 1.50140941f);
  } else {
    w = sqrtf(w) - 3.0f;
    p = -0.000200214257f;
    p = fmaf(p, w, 0.000100950558f);
    p = fmaf(p, w, 0.00134934322f);
    p = fmaf(p, w, -0.00367342844f);
    p = fmaf(p, w, 0.00573950773f);
    p = fmaf(p, w, -0.0076224613f);
    p = fmaf(p, w, 0.00943887047f);
    p = fmaf(p, w, 1.00167406f);
    p = fmaf(p, w, 2.83297682f);
  }
  return p * x;
}

// Fused: blocks 0..31 -> state = sv@T^T + z@chol(Q) (z regenerated per thread);
//        blocks 32..127 -> Ht (column-major transpose of H, 3 x 8192)
__global__ void __launch_bounds__(256) k_prep(uint32_t k0, uint32_t k1,
                                              const float* __restrict__ sv,
                                              const float* __restrict__ T,
                                              const float* __restrict__ Q,
                                              const float* __restrict__ H,
                                              float* __restrict__ st,
                                              float* __restrict__ ht) {
  int b = blockIdx.x;
  if (b < 32) {
    int i = b * 256 + threadIdx.x;  // particle
    const float lo = -0.99999994f;  // nextafter(-1,0)
    float zz[3];
#pragma unroll
    for (int k = 0; k < 3; k++) {
      uint32_t bits = tf_bits(k0, k1, 3u * (uint32_t)i + (uint32_t)k);
      float v = fmaxf(lo, u01(bits) * 2.0f + lo);  // span fp32(1-lo) == 2.0
      zz[k] = 1.41421356f * erfinvf_(v);           // fp32(sqrt(2))
    }
    float L00 = sqrtf(Q[0]);
    float L10 = Q[3] / L00, L20 = Q[6] / L00;
    float L11 = sqrtf(Q[4] - L10 * L10);
    float L21 = (Q[7] - L20 * L10) / L11;
    float L22 = sqrtf(Q[8] - L20 * L20 - L21 * L21);
    float s0 = sv[i * 3], s1 = sv[i * 3 + 1], s2 = sv[i * 3 + 2];
    float u0 = s0 * T[0] + s1 * T[1] + s2 * T[2];
    float u1 = s0 * T[3] + s1 * T[4] + s2 * T[5];
    float u2 = s0 * T[6] + s1 * T[7] + s2 * T[8];
    st[i * 3]     = u0 + (zz[0] * L00 + zz[1] * L10 + zz[2] * L20);
    st[i * 3 + 1] = u1 + (zz[1] * L11 + zz[2] * L21);
    st[i * 3 + 2] = u2 + (zz[2] * L22);
  } else {
    int t = (b - 32) * 256 + threadIdx.x;  // 0..24575
    int k = t >> 13, j = t & (NP - 1);
    ht[t] = H[j * 3 + k];  // ht[k*8192 + j] = H[j][k]
  }
}

// ---------- k_fused: weights (HBM) || RNG E-gen for samples 0..6143 (VALU) ----
// R5 POST-MORTEM FIX: role assignment by raw b%4 aliased with the XCD
// round-robin (blockIdx%8): all weights blocks landed on XCDs {0,4}, which
// then did the whole 256MB `in` stream on 64 CUs (k_fused 318us, VALUBusy 39%).
// Relabel through the bijective XCD-preserving swizzle vb = (b&7)*1024 + b>>3:
// each XCD gets a contiguous 1024-slab of vb -> 256 weights + 768 RNG blocks
// per XCD, and each XCD's weights stream a contiguous 1024-row (32MB) slab of
// `in` (L2-local). Pure relabeling — same (role,w,s) set, bit-exact.
__global__ void __launch_bounds__(256) k_fused(uint32_t k0, uint32_t k1,
                                               const float* __restrict__ in,
                                               const float* __restrict__ ht,
                                               const float* __restrict__ st,
                                               float* __restrict__ winv,
                                               float* __restrict__ E) {
  int b = blockIdx.x;
  int vb = (b & 7) * 1024 + (b >> 3);     // bijective on [0,8192)
  if ((vb & 3) == 0) {
    // ---- weights role (proven round-1 body) ----
    int w = vb >> 2;
    int wave = threadIdx.x >> 6;
    int lane = threadIdx.x & 63;
    int row = w * 4 + wave;
    float s0 = st[row * 3], s1 = st[row * 3 + 1], s2 = st[row * 3 + 2];
    const float4* inrow = (const float4*)(in + (size_t)row * NC);
    const float4* h0 = (const float4*)ht;
    const float4* h1 = (const float4*)(ht + NC);
    const float4* h2 = (const float4*)(ht + 2 * NC);
    float acc = 0.0f;
#pragma unroll 4
    for (int it = lane; it < NC / 4; it += 64) {
      float4 x = inrow[it];
      float4 a = h0[it];
      float4 bb = h1[it];
      float4 c = h2[it];
      float d0 = x.x - (a.x * s0 + bb.x * s1 + c.x * s2);
      float d1 = x.y - (a.y * s0 + bb.y * s1 + c.y * s2);
      float d2 = x.z - (a.z * s0 + bb.z * s1 + c.z * s2);
      float d3 = x.w - (a.w * s0 + bb.w * s1 + c.w * s2);
      acc += d0 * d0 + d1 * d1 + d2 * d2 + d3 * d3;
    }
#pragma unroll
    for (int off = 32; off > 0; off >>= 1) acc += __shfl_down(acc, off, 64);
    if (lane == 0) winv[row] = 1.0f / acc;
  } else {
    // ---- RNG role: E[s][i] = -log(u_{s,i}), 4 consecutive i per thread ----
    int s = vb - (vb >> 2) - 1;             // bijective onto 0..6143
    uint32_t base = (uint32_t)s * (uint32_t)NP;
    float4* erow = (float4*)(E + (size_t)s * NP);
#pragma unroll 2
    for (int p = 0; p < 8; ++p) {
      uint32_t i0 = (uint32_t)(p * 1024 + 4 * threadIdx.x);
      float4 e;
      e.x = egen(k0, k1, base + i0);
      e.y = egen(k0, k1, base + i0 + 1u);
      e.z = egen(k0, k1, base + i0 + 2u);
      e.w = egen(k0, k1, base + i0 + 3u);
      erow[i0 >> 2] = e;
    }
  }
}

// ---------- k_race: E-race (mem-bound) || direct hash-race (VALU-bound) ------
// 3584 blocks, period-7 interleave (3 E-blocks : 4 direct-blocks); 7 is
// co-prime with 8 XCDs so both roles spread evenly (checked post-R5).
__global__ void __launch_bounds__(256) k_race(uint32_t k0, uint32_t k1,
                                              const float* __restrict__ E,
                                              const float* __restrict__ winv,
                                              int* __restrict__ idx) {
  int b = blockIdx.x;
  int m = b % 7;
  if (m < 3) {
    // ---- E-path: samples 4e..4e+3, e = 3*(b/7)+m in 0..1535 ----
    int e = (b / 7) * 3 + m;
    int wave = threadIdx.x >> 6;
    int lane = threadIdx.x & 63;
    int s = e * 4 + wave;                   // 0..6143
    const float4* erow = (const float4*)(E + (size_t)s * NP);
    const float4* wv = (const float4*)winv;
    float best = 3.4e38f;
    int bi = 0;
#pragma unroll 4
    for (int it = lane; it < NP / 4; it += 64) {
      float4 ev = erow[it];
      float4 w = wv[it];
      int i = it * 4;
      float r0 = ev.x * w.x;
      float r1 = ev.y * w.y;
      float r2 = ev.z * w.z;
      float r3 = ev.w * w.w;
      if (r0 < best) { best = r0; bi = i; }
      if (r1 < best) { best = r1; bi = i + 1; }
      if (r2 < best) { best = r2; bi = i + 2; }
      if (r3 < best) { best = r3; bi = i + 3; }
    }
#pragma unroll
    for (int off = 32; off > 0; off >>= 1) {
      float ob = __shfl_down(best, off, 64);
      int oi = __shfl_down(bi, off, 64);
      if (ob < best || (ob == best && oi < bi)) { best = ob; bi = oi; }
    }
    if (lane == 0) idx[s] = bi;
  } else {
    // ---- direct path: sample s = 6144 + 4*(b/7) + (m-3), round-0 body ----
    uint32_t s = (uint32_t)(NS_E + (b / 7) * 4 + (m - 3));   // 6144..8191
    uint32_t base = s * (uint32_t)NP;
    const float TINY = 1.17549435e-38f;
    float best = 3.4e38f;
    int bi = 0;
#pragma unroll 4
    for (uint32_t i = threadIdx.x; i < NP; i += 256) {
      uint32_t bits = tf_bits(k0, k1, base + i);
      float v = fmaxf(u01(bits), TINY);
      float r = -__logf(v) * winv[i];
      if (r < best) { best = r; bi = (int)i; }  // strict <: lowest i wins
    }
    __shared__ float rv[256];
    __shared__ int ri[256];
    rv[threadIdx.x] = best;
    ri[threadIdx.x] = bi;
    __syncthreads();
    for (int stp = 128; stp > 0; stp >>= 1) {
      if (threadIdx.x < stp) {
        float va = rv[threadIdx.x], vb = rv[threadIdx.x + stp];
        int ia = ri[threadIdx.x], ib = ri[threadIdx.x + stp];
        if (vb < va || (vb == va && ib < ia)) { rv[threadIdx.x] = vb; ri[threadIdx.x] = ib; }
      }
      __syncthreads();
    }
    if (threadIdx.x == 0) idx[s] = ri[0];
  }
}

// out = mean over s of state[idx[s]]
__global__ void __launch_bounds__(1024) k_mean(const float* __restrict__ st,
                                               const int* __restrict__ idx,
                                               float* __restrict__ out) {
  double a0 = 0, a1 = 0, a2 = 0;
  for (int s = threadIdx.x; s < NP; s += 1024) {
    int j = idx[s];
    a0 += st[j * 3];
    a1 += st[j * 3 + 1];
    a2 += st[j * 3 + 2];
  }
  __shared__ double r0[1024], r1[1024], r2[1024];
  r0[threadIdx.x] = a0; r1[threadIdx.x] = a1; r2[threadIdx.x] = a2;
  __syncthreads();
  for (int s = 512; s > 0; s >>= 1) {
    if (threadIdx.x < s) {
      r0[threadIdx.x] += r0[threadIdx.x + s];
      r1[threadIdx.x] += r1[threadIdx.x + s];
      r2[threadIdx.x] += r2[threadIdx.x + s];
    }
    __syncthreads();
  }
  if (threadIdx.x == 0) {
    out[0] = (float)(r0[0] / NP);
    out[1] = (float)(r1[0] / NP);
    out[2] = (float)(r2[0] / NP);
  }
}

// ---------------- fallback path (ws too small): original kernels --------------
__global__ void __launch_bounds__(256) k_weights(const float* __restrict__ in,
                                                 const float* __restrict__ ht,
                                                 const float* __restrict__ st,
                                                 float* __restrict__ winv) {
  int wave = threadIdx.x >> 6;
  int lane = threadIdx.x & 63;
  int row = blockIdx.x * 4 + wave;
  float s0 = st[row * 3], s1 = st[row * 3 + 1], s2 = st[row * 3 + 2];
  const float4* inrow = (const float4*)(in + (size_t)row * NC);
  const float4* h0 = (const float4*)ht;
  const float4* h1 = (const float4*)(ht + NC);
  const float4* h2 = (const float4*)(ht + 2 * NC);
  float acc = 0.0f;
#pragma unroll 4
  for (int it = lane; it < NC / 4; it += 64) {
    float4 x = inrow[it];
    float4 a = h0[it];
    float4 b = h1[it];
    float4 c = h2[it];
    float d0 = x.x - (a.x * s0 + b.x * s1 + c.x * s2);
    float d1 = x.y - (a.y * s0 + b.y * s1 + c.y * s2);
    float d2 = x.z - (a.z * s0 + b.z * s1 + c.z * s2);
    float d3 = x.w - (a.w * s0 + b.w * s1 + c.w * s2);
    acc += d0 * d0 + d1 * d1 + d2 * d2 + d3 * d3;
  }
#pragma unroll
  for (int off = 32; off > 0; off >>= 1) acc += __shfl_down(acc, off, 64);
  if (lane == 0) winv[row] = 1.0f / acc;
}

__global__ void __launch_bounds__(256) k_resample(uint32_t k0, uint32_t k1,
                                                  const float* __restrict__ winv,
                                                  int* __restrict__ idx) {
  uint32_t s = blockIdx.x;
  uint32_t base = s * (uint32_t)NP;
  const float TINY = 1.17549435e-38f;
  float best = 3.4e38f;
  int bi = 0;
#pragma unroll 4
  for (uint32_t i = threadIdx.x; i < NP; i += 256) {
    uint32_t bits = tf_bits(k0, k1, base + i);
    float v = fmaxf(u01(bits), TINY);
    float r = -__logf(v) * winv[i];
    if (r < best) { best = r; bi = (int)i; }
  }
  __shared__ float rv[256];
  __shared__ int ri[256];
  rv[threadIdx.x] = best;
  ri[threadIdx.x] = bi;
  __syncthreads();
  for (int stp = 128; stp > 0; stp >>= 1) {
    if (threadIdx.x < stp) {
      float va = rv[threadIdx.x], vb = rv[threadIdx.x + stp];
      int ia = ri[threadIdx.x], ib = ri[threadIdx.x + stp];
      if (vb < va || (vb == va && ib < ia)) { rv[threadIdx.x] = vb; ri[threadIdx.x] = ib; }
    }
    __syncthreads();
  }
  if (threadIdx.x == 0) idx[s] = ri[0];
}

extern "C" void kernel_launch(void* const* d_in, const int* in_sizes, int n_in,
                              void* d_out, int out_size, void* d_ws, size_t ws_size,
                              hipStream_t stream) {
  const float* in = (const float*)d_in[0];   // (1, C, P)
  const float* sv = (const float*)d_in[1];   // (P, 3)
  const float* T  = (const float*)d_in[2];   // (3, 3)
  const float* Q  = (const float*)d_in[3];   // (3, 3)
  const float* H  = (const float*)d_in[4];   // (C, 3)
  float* out = (float*)d_out;                // (3,)

  // partitionable split(key(42)): subkey j = threefry(key, (0, j)) both outputs
  uint32_t nk0, nk1, ck0, ck1;
  threefry2x32(0u, 42u, 0u, 0u, nk0, nk1);  // k_noise
  threefry2x32(0u, 42u, 0u, 1u, ck0, ck1);  // k_cat

  const size_t eFloats = (size_t)NP * (size_t)NP;        // full 8192-row layout
  const size_t tailBytes = (24576 + 24576 + NP + NP) * 4; // st+ht+winv+idx
  const bool fused = ws_size >= eFloats * 4 + tailBytes;

  if (fused) {
    float* E    = (float*)d_ws;          // 256 MB (only rows 0..6143 used)
    float* st   = E + eFloats;           // 24576 f
    float* ht   = st + 24576;            // 24576 f
    float* winv = ht + 24576;            // 8192 f
    int*   idx  = (int*)(winv + NP);     // 8192 i

    hipLaunchKernelGGL(k_prep, dim3(128), dim3(256), 0, stream, nk0, nk1, sv, T, Q, H, st, ht);
    hipLaunchKernelGGL(k_fused, dim3(8192), dim3(256), 0, stream, ck0, ck1, in, ht, st, winv, E);
    hipLaunchKernelGGL(k_race, dim3(3584), dim3(256), 0, stream, ck0, ck1, E, winv, idx);
    hipLaunchKernelGGL(k_mean, dim3(1), dim3(1024), 0, stream, st, idx, out);
  } else {
    float* st   = (float*)d_ws;          // 24576 f
    float* ht   = st + 24576;            // 24576 f
    float* winv = ht + 24576;            // 8192 f
    int*   idx  = (int*)(winv + NP);     // 8192 i

    hipLaunchKernelGGL(k_prep, dim3(128), dim3(256), 0, stream, nk0, nk1, sv, T, Q, H, st, ht);
    hipLaunchKernelGGL(k_weights, dim3(NP / 4), dim3(256), 0, stream, in, ht, st, winv);
    hipLaunchKernelGGL(k_resample, dim3(NP), dim3(256), 0, stream, ck0, ck1, winv, idx);
    hipLaunchKernelGGL(k_mean, dim3(1), dim3(1024), 0, stream, st, idx, out);
  }
}

// Round 7
// 486.628 us; speedup vs baseline: 1.3827x; 1.3827x over previous
//
#include <hip/hip_runtime.h>
#include <stdint.h>

#define NP 8192           // particles
#define NC 8192           // channels
#define NS_E 6144         // samples materialized via E in k_fused (rows 0..6143)
#define NS_D 2048         // samples computed directly in k_race (6144..8191)

__host__ __device__ inline uint32_t rotl32(uint32_t x, int r) {
  return __builtin_rotateleft32(x, (unsigned)r);   // lowers to v_alignbit_b32 (verified R4)
}

// JAX threefry2x32: 20 rounds, key schedule injection every 4 rounds.
__host__ __device__ inline void threefry2x32(uint32_t k0, uint32_t k1,
                                             uint32_t x0, uint32_t x1,
                                             uint32_t& o0, uint32_t& o1) {
  uint32_t ks2 = k0 ^ k1 ^ 0x1BD11BDAu;
  x0 += k0; x1 += k1;
#define TF_R(r) { x0 += x1; x1 = rotl32(x1, (r)); x1 ^= x0; }
  TF_R(13) TF_R(15) TF_R(26) TF_R(6)   x0 += k1;  x1 += ks2 + 1u;
  TF_R(17) TF_R(29) TF_R(16) TF_R(24)  x0 += ks2; x1 += k0 + 2u;
  TF_R(13) TF_R(15) TF_R(26) TF_R(6)   x0 += k0;  x1 += k1 + 3u;
  TF_R(17) TF_R(29) TF_R(16) TF_R(24)  x0 += k1;  x1 += ks2 + 4u;
  TF_R(13) TF_R(15) TF_R(26) TF_R(6)   x0 += ks2; x1 += k0 + 5u;
#undef TF_R
  o0 = x0; o1 = x1;
}

// partitionable threefry random_bits, 32-bit: counter=(0,i), bits = o0 ^ o1
__device__ inline uint32_t tf_bits(uint32_t k0, uint32_t k1, uint32_t i) {
  uint32_t o0, o1;
  threefry2x32(k0, k1, 0u, i, o0, o1);
  return o0 ^ o1;
}

// uniform [0,1): (bits>>9)|0x3f800000 -> [1,2) -> -1
__device__ inline float u01(uint32_t bits) {
  return __uint_as_float((bits >> 9) | 0x3f800000u) - 1.0f;
}

// E = -log(uniform(tiny,1)); fl((-L)*w) == -fl(L*w) (IEEE sign symmetry), so
// E-then-multiply preserves the original fused -log(v)*winv argmin bit-for-bit.
__device__ inline float egen(uint32_t k0, uint32_t k1, uint32_t ctr) {
  const float TINY = 1.17549435e-38f;
  uint32_t bits = tf_bits(k0, k1, ctr);
  float v = fmaxf(u01(bits), TINY);
  return -__logf(v);
}

// XLA ErfInv32 (Giles) polynomial
__device__ inline float erfinvf_(float x) {
  float w = -log1pf(-x * x);
  float p;
  if (w < 5.0f) {
    w -= 2.5f;
    p = 2.81022636e-08f;
    p = fmaf(p, w, 3.43273939e-07f);
    p = fmaf(p, w, -3.5233877e-06f);
    p = fmaf(p, w, -4.39150654e-06f);
    p = fmaf(p, w, 0.00021858087f);
    p = fmaf(p, w, -0.00125372503f);
    p = fmaf(p, w, -0.00417768164f);
    p = fmaf(p, w, 0.246640727f);
    p = fmaf(p, w, 1.50140941f);
  } else {
    w = sqrtf(w) - 3.0f;
    p = -0.000200214257f;
    p = fmaf(p, w, 0.000100950558f);
    p = fmaf(p, w, 0.00134934322f);
    p = fmaf(p, w, -0.00367342844f);
    p = fmaf(p, w, 0.00573950773f);
    p = fmaf(p, w, -0.0076224613f);
    p = fmaf(p, w, 0.00943887047f);
    p = fmaf(p, w, 1.00167406f);
    p = fmaf(p, w, 2.83297682f);
  }
  return p * x;
}

// Fused: blocks 0..31 -> state = sv@T^T + z@chol(Q) (z regenerated per thread);
//        blocks 32..127 -> Ht (column-major transpose of H, 3 x 8192)
__global__ void __launch_bounds__(256) k_prep(uint32_t k0, uint32_t k1,
                                              const float* __restrict__ sv,
                                              const float* __restrict__ T,
                                              const float* __restrict__ Q,
                                              const float* __restrict__ H,
                                              float* __restrict__ st,
                                              float* __restrict__ ht) {
  int b = blockIdx.x;
  if (b < 32) {
    int i = b * 256 + threadIdx.x;  // particle
    const float lo = -0.99999994f;  // nextafter(-1,0)
    float zz[3];
#pragma unroll
    for (int k = 0; k < 3; k++) {
      uint32_t bits = tf_bits(k0, k1, 3u * (uint32_t)i + (uint32_t)k);
      float v = fmaxf(lo, u01(bits) * 2.0f + lo);  // span fp32(1-lo) == 2.0
      zz[k] = 1.41421356f * erfinvf_(v);           // fp32(sqrt(2))
    }
    float L00 = sqrtf(Q[0]);
    float L10 = Q[3] / L00, L20 = Q[6] / L00;
    float L11 = sqrtf(Q[4] - L10 * L10);
    float L21 = (Q[7] - L20 * L10) / L11;
    float L22 = sqrtf(Q[8] - L20 * L20 - L21 * L21);
    float s0 = sv[i * 3], s1 = sv[i * 3 + 1], s2 = sv[i * 3 + 2];
    float u0 = s0 * T[0] + s1 * T[1] + s2 * T[2];
    float u1 = s0 * T[3] + s1 * T[4] + s2 * T[5];
    float u2 = s0 * T[6] + s1 * T[7] + s2 * T[8];
    st[i * 3]     = u0 + (zz[0] * L00 + zz[1] * L10 + zz[2] * L20);
    st[i * 3 + 1] = u1 + (zz[1] * L11 + zz[2] * L21);
    st[i * 3 + 2] = u2 + (zz[2] * L22);
  } else {
    int t = (b - 32) * 256 + threadIdx.x;  // 0..24575
    int k = t >> 13, j = t & (NP - 1);
    ht[t] = H[j * 3 + k];  // ht[k*8192 + j] = H[j][k]
  }
}

// ---------- k_fused v2: WAVE-level role mix (robust to any XCD mapping) ------
// R5/R6 POST-MORTEM: block-level role patterns (b%4, XCD swizzle) collapsed the
// hash-wave residency share on some XCD subsets (k_fused 318/336us, VALUBusy
// 36-39%) under an unknown blockIdx->XCD granularity. Fix: every block is
// IDENTICAL — wave 0 computes one weights row (row = blockIdx), waves 1..3
// generate three quarter-rows of E. 8192 blocks x 1 row = 8192 rows; 8192 x 3
// waves = 24576 quarters = 6144 E rows. The 1:3 weights:hash wave mix holds on
// every CU of every XCD regardless of dispatch mapping. Weights-row FP order
// identical to the proven per-wave body; E content bit-identical (same ctr).
__global__ void __launch_bounds__(256) k_fused(uint32_t k0, uint32_t k1,
                                               const float* __restrict__ in,
                                               const float* __restrict__ ht,
                                               const float* __restrict__ st,
                                               float* __restrict__ winv,
                                               float* __restrict__ E) {
  int wave = threadIdx.x >> 6;
  int lane = threadIdx.x & 63;
  if (wave == 0) {
    // ---- weights role: one row per block (proven per-wave body) ----
    int row = blockIdx.x;
    float s0 = st[row * 3], s1 = st[row * 3 + 1], s2 = st[row * 3 + 2];
    const float4* inrow = (const float4*)(in + (size_t)row * NC);
    const float4* h0 = (const float4*)ht;
    const float4* h1 = (const float4*)(ht + NC);
    const float4* h2 = (const float4*)(ht + 2 * NC);
    float acc = 0.0f;
#pragma unroll 4
    for (int it = lane; it < NC / 4; it += 64) {
      float4 x = inrow[it];
      float4 a = h0[it];
      float4 bb = h1[it];
      float4 c = h2[it];
      float d0 = x.x - (a.x * s0 + bb.x * s1 + c.x * s2);
      float d1 = x.y - (a.y * s0 + bb.y * s1 + c.y * s2);
      float d2 = x.z - (a.z * s0 + bb.z * s1 + c.z * s2);
      float d3 = x.w - (a.w * s0 + bb.w * s1 + c.w * s2);
      acc += d0 * d0 + d1 * d1 + d2 * d2 + d3 * d3;
    }
#pragma unroll
    for (int off = 32; off > 0; off >>= 1) acc += __shfl_down(acc, off, 64);
    if (lane == 0) winv[row] = 1.0f / acc;
  } else {
    // ---- RNG role: quarter-sample per wave ----
    int gw = blockIdx.x * 3 + (wave - 1);   // 0..24575
    int s = gw >> 2;                        // 0..6143
    int q = gw & 3;                         // quarter within sample
    uint32_t base = (uint32_t)s * (uint32_t)NP;
    float4* erow = (float4*)(E + (size_t)s * NP);
#pragma unroll 2
    for (int p = 0; p < 8; ++p) {
      uint32_t i0 = (uint32_t)(q * 2048 + p * 256 + 4 * lane);
      float4 e;
      e.x = egen(k0, k1, base + i0);
      e.y = egen(k0, k1, base + i0 + 1u);
      e.z = egen(k0, k1, base + i0 + 2u);
      e.w = egen(k0, k1, base + i0 + 3u);
      erow[i0 >> 2] = e;
    }
  }
}

// ---------- k_race: E-race (mem-bound) || direct hash-race (VALU-bound) ------
// 3584 blocks, period-7 interleave (3 E-blocks : 4 direct-blocks); 7 is
// coprime with any power-of-2 dispatch granularity. Verified bit-exact R5/R6.
__global__ void __launch_bounds__(256) k_race(uint32_t k0, uint32_t k1,
                                              const float* __restrict__ E,
                                              const float* __restrict__ winv,
                                              int* __restrict__ idx) {
  int b = blockIdx.x;
  int m = b % 7;
  if (m < 3) {
    // ---- E-path: samples 4e..4e+3, e = 3*(b/7)+m in 0..1535 ----
    int e = (b / 7) * 3 + m;
    int wave = threadIdx.x >> 6;
    int lane = threadIdx.x & 63;
    int s = e * 4 + wave;                   // 0..6143
    const float4* erow = (const float4*)(E + (size_t)s * NP);
    const float4* wv = (const float4*)winv;
    float best = 3.4e38f;
    int bi = 0;
#pragma unroll 4
    for (int it = lane; it < NP / 4; it += 64) {
      float4 ev = erow[it];
      float4 w = wv[it];
      int i = it * 4;
      float r0 = ev.x * w.x;
      float r1 = ev.y * w.y;
      float r2 = ev.z * w.z;
      float r3 = ev.w * w.w;
      if (r0 < best) { best = r0; bi = i; }
      if (r1 < best) { best = r1; bi = i + 1; }
      if (r2 < best) { best = r2; bi = i + 2; }
      if (r3 < best) { best = r3; bi = i + 3; }
    }
#pragma unroll
    for (int off = 32; off > 0; off >>= 1) {
      float ob = __shfl_down(best, off, 64);
      int oi = __shfl_down(bi, off, 64);
      if (ob < best || (ob == best && oi < bi)) { best = ob; bi = oi; }
    }
    if (lane == 0) idx[s] = bi;
  } else {
    // ---- direct path: sample s = 6144 + 4*(b/7) + (m-3), round-0 body ----
    uint32_t s = (uint32_t)(NS_E + (b / 7) * 4 + (m - 3));   // 6144..8191
    uint32_t base = s * (uint32_t)NP;
    const float TINY = 1.17549435e-38f;
    float best = 3.4e38f;
    int bi = 0;
#pragma unroll 4
    for (uint32_t i = threadIdx.x; i < NP; i += 256) {
      uint32_t bits = tf_bits(k0, k1, base + i);
      float v = fmaxf(u01(bits), TINY);
      float r = -__logf(v) * winv[i];
      if (r < best) { best = r; bi = (int)i; }  // strict <: lowest i wins
    }
    __shared__ float rv[256];
    __shared__ int ri[256];
    rv[threadIdx.x] = best;
    ri[threadIdx.x] = bi;
    __syncthreads();
    for (int stp = 128; stp > 0; stp >>= 1) {
      if (threadIdx.x < stp) {
        float va = rv[threadIdx.x], vb = rv[threadIdx.x + stp];
        int ia = ri[threadIdx.x], ib = ri[threadIdx.x + stp];
        if (vb < va || (vb == va && ib < ia)) { rv[threadIdx.x] = vb; ri[threadIdx.x] = ib; }
      }
      __syncthreads();
    }
    if (threadIdx.x == 0) idx[s] = ri[0];
  }
}

// out = mean over s of state[idx[s]]
__global__ void __launch_bounds__(1024) k_mean(const float* __restrict__ st,
                                               const int* __restrict__ idx,
                                               float* __restrict__ out) {
  double a0 = 0, a1 = 0, a2 = 0;
  for (int s = threadIdx.x; s < NP; s += 1024) {
    int j = idx[s];
    a0 += st[j * 3];
    a1 += st[j * 3 + 1];
    a2 += st[j * 3 + 2];
  }
  __shared__ double r0[1024], r1[1024], r2[1024];
  r0[threadIdx.x] = a0; r1[threadIdx.x] = a1; r2[threadIdx.x] = a2;
  __syncthreads();
  for (int s = 512; s > 0; s >>= 1) {
    if (threadIdx.x < s) {
      r0[threadIdx.x] += r0[threadIdx.x + s];
      r1[threadIdx.x] += r1[threadIdx.x + s];
      r2[threadIdx.x] += r2[threadIdx.x + s];
    }
    __syncthreads();
  }
  if (threadIdx.x == 0) {
    out[0] = (float)(r0[0] / NP);
    out[1] = (float)(r1[0] / NP);
    out[2] = (float)(r2[0] / NP);
  }
}

// ---------------- fallback path (ws too small): original kernels --------------
__global__ void __launch_bounds__(256) k_weights(const float* __restrict__ in,
                                                 const float* __restrict__ ht,
                                                 const float* __restrict__ st,
                                                 float* __restrict__ winv) {
  int wave = threadIdx.x >> 6;
  int lane = threadIdx.x & 63;
  int row = blockIdx.x * 4 + wave;
  float s0 = st[row * 3], s1 = st[row * 3 + 1], s2 = st[row * 3 + 2];
  const float4* inrow = (const float4*)(in + (size_t)row * NC);
  const float4* h0 = (const float4*)ht;
  const float4* h1 = (const float4*)(ht + NC);
  const float4* h2 = (const float4*)(ht + 2 * NC);
  float acc = 0.0f;
#pragma unroll 4
  for (int it = lane; it < NC / 4; it += 64) {
    float4 x = inrow[it];
    float4 a = h0[it];
    float4 b = h1[it];
    float4 c = h2[it];
    float d0 = x.x - (a.x * s0 + b.x * s1 + c.x * s2);
    float d1 = x.y - (a.y * s0 + b.y * s1 + c.y * s2);
    float d2 = x.z - (a.z * s0 + b.z * s1 + c.z * s2);
    float d3 = x.w - (a.w * s0 + b.w * s1 + c.w * s2);
    acc += d0 * d0 + d1 * d1 + d2 * d2 + d3 * d3;
  }
#pragma unroll
  for (int off = 32; off > 0; off >>= 1) acc += __shfl_down(acc, off, 64);
  if (lane == 0) winv[row] = 1.0f / acc;
}

__global__ void __launch_bounds__(256) k_resample(uint32_t k0, uint32_t k1,
                                                  const float* __restrict__ winv,
                                                  int* __restrict__ idx) {
  uint32_t s = blockIdx.x;
  uint32_t base = s * (uint32_t)NP;
  const float TINY = 1.17549435e-38f;
  float best = 3.4e38f;
  int bi = 0;
#pragma unroll 4
  for (uint32_t i = threadIdx.x; i < NP; i += 256) {
    uint32_t bits = tf_bits(k0, k1, base + i);
    float v = fmaxf(u01(bits), TINY);
    float r = -__logf(v) * winv[i];
    if (r < best) { best = r; bi = (int)i; }
  }
  __shared__ float rv[256];
  __shared__ int ri[256];
  rv[threadIdx.x] = best;
  ri[threadIdx.x] = bi;
  __syncthreads();
  for (int stp = 128; stp > 0; stp >>= 1) {
    if (threadIdx.x < stp) {
      float va = rv[threadIdx.x], vb = rv[threadIdx.x + stp];
      int ia = ri[threadIdx.x], ib = ri[threadIdx.x + stp];
      if (vb < va || (vb == va && ib < ia)) { rv[threadIdx.x] = vb; ri[threadIdx.x] = ib; }
    }
    __syncthreads();
  }
  if (threadIdx.x == 0) idx[s] = ri[0];
}

extern "C" void kernel_launch(void* const* d_in, const int* in_sizes, int n_in,
                              void* d_out, int out_size, void* d_ws, size_t ws_size,
                              hipStream_t stream) {
  const float* in = (const float*)d_in[0];   // (1, C, P)
  const float* sv = (const float*)d_in[1];   // (P, 3)
  const float* T  = (const float*)d_in[2];   // (3, 3)
  const float* Q  = (const float*)d_in[3];   // (3, 3)
  const float* H  = (const float*)d_in[4];   // (C, 3)
  float* out = (float*)d_out;                // (3,)

  // partitionable split(key(42)): subkey j = threefry(key, (0, j)) both outputs
  uint32_t nk0, nk1, ck0, ck1;
  threefry2x32(0u, 42u, 0u, 0u, nk0, nk1);  // k_noise
  threefry2x32(0u, 42u, 0u, 1u, ck0, ck1);  // k_cat

  const size_t eFloats = (size_t)NP * (size_t)NP;        // full 8192-row layout
  const size_t tailBytes = (24576 + 24576 + NP + NP) * 4; // st+ht+winv+idx
  const bool fused = ws_size >= eFloats * 4 + tailBytes;

  if (fused) {
    float* E    = (float*)d_ws;          // 256 MB (only rows 0..6143 used)
    float* st   = E + eFloats;           // 24576 f
    float* ht   = st + 24576;            // 24576 f
    float* winv = ht + 24576;            // 8192 f
    int*   idx  = (int*)(winv + NP);     // 8192 i

    hipLaunchKernelGGL(k_prep, dim3(128), dim3(256), 0, stream, nk0, nk1, sv, T, Q, H, st, ht);
    hipLaunchKernelGGL(k_fused, dim3(8192), dim3(256), 0, stream, ck0, ck1, in, ht, st, winv, E);
    hipLaunchKernelGGL(k_race, dim3(3584), dim3(256), 0, stream, ck0, ck1, E, winv, idx);
    hipLaunchKernelGGL(k_mean, dim3(1), dim3(1024), 0, stream, st, idx, out);
  } else {
    float* st   = (float*)d_ws;          // 24576 f
    float* ht   = st + 24576;            // 24576 f
    float* winv = ht + 24576;            // 8192 f
    int*   idx  = (int*)(winv + NP);     // 8192 i

    hipLaunchKernelGGL(k_prep, dim3(128), dim3(256), 0, stream, nk0, nk1, sv, T, Q, H, st, ht);
    hipLaunchKernelGGL(k_weights, dim3(NP / 4), dim3(256), 0, stream, in, ht, st, winv);
    hipLaunchKernelGGL(k_resample, dim3(NP), dim3(256), 0, stream, ck0, ck1, winv, idx);
    hipLaunchKernelGGL(k_mean, dim3(1), dim3(1024), 0, stream, st, idx, out);
  }
}

// Round 8
// 485.545 us; speedup vs baseline: 1.3858x; 1.0022x over previous
//
#include <hip/hip_runtime.h>
#include <stdint.h>

#define NP 8192           // particles
#define NC 8192           // channels
#define NS_E 6144         // samples materialized via E in k_fused (rows 0..6143)
#define NS_D 2048         // samples computed directly in k_race (6144..8191)

__host__ __device__ inline uint32_t rotl32(uint32_t x, int r) {
  return __builtin_rotateleft32(x, (unsigned)r);   // lowers to v_alignbit_b32 (verified R4)
}

// JAX threefry2x32: 20 rounds, key schedule injection every 4 rounds.
__host__ __device__ inline void threefry2x32(uint32_t k0, uint32_t k1,
                                             uint32_t x0, uint32_t x1,
                                             uint32_t& o0, uint32_t& o1) {
  uint32_t ks2 = k0 ^ k1 ^ 0x1BD11BDAu;
  x0 += k0; x1 += k1;
#define TF_R(r) { x0 += x1; x1 = rotl32(x1, (r)); x1 ^= x0; }
  TF_R(13) TF_R(15) TF_R(26) TF_R(6)   x0 += k1;  x1 += ks2 + 1u;
  TF_R(17) TF_R(29) TF_R(16) TF_R(24)  x0 += ks2; x1 += k0 + 2u;
  TF_R(13) TF_R(15) TF_R(26) TF_R(6)   x0 += k0;  x1 += k1 + 3u;
  TF_R(17) TF_R(29) TF_R(16) TF_R(24)  x0 += k1;  x1 += ks2 + 4u;
  TF_R(13) TF_R(15) TF_R(26) TF_R(6)   x0 += ks2; x1 += k0 + 5u;
#undef TF_R
  o0 = x0; o1 = x1;
}

// partitionable threefry random_bits, 32-bit: counter=(0,i), bits = o0 ^ o1
__device__ inline uint32_t tf_bits(uint32_t k0, uint32_t k1, uint32_t i) {
  uint32_t o0, o1;
  threefry2x32(k0, k1, 0u, i, o0, o1);
  return o0 ^ o1;
}

// 8-way interleaved threefry: 8 INDEPENDENT chains, round-major instruction
// order, so the SIMD always has 8 ready ops despite the 4-cyc dependent-op
// latency (R7 theory: single-chain code was latency-bound at ~2.9x the issue
// floor). Caller pre-injects the key: x0[c]=k0 (counter x0=0), x1[c]=ctr+k1.
// Same counters -> bit-identical outputs to the scalar tf_bits.
__device__ inline void tf20x8(uint32_t k0, uint32_t k1,
                              uint32_t x0[8], uint32_t x1[8]) {
  uint32_t ks2 = k0 ^ k1 ^ 0x1BD11BDAu;
#define TFR8(r) _Pragma("unroll") for (int c = 0; c < 8; c++) { x0[c] += x1[c]; x1[c] = rotl32(x1[c], (r)); x1[c] ^= x0[c]; }
#define INJ8(a, b, t) _Pragma("unroll") for (int c = 0; c < 8; c++) { x0[c] += (a); x1[c] += (b) + (t); }
  TFR8(13) TFR8(15) TFR8(26) TFR8(6)  INJ8(k1, ks2, 1u)
  TFR8(17) TFR8(29) TFR8(16) TFR8(24) INJ8(ks2, k0, 2u)
  TFR8(13) TFR8(15) TFR8(26) TFR8(6)  INJ8(k0, k1, 3u)
  TFR8(17) TFR8(29) TFR8(16) TFR8(24) INJ8(k1, ks2, 4u)
  TFR8(13) TFR8(15) TFR8(26) TFR8(6)  INJ8(ks2, k0, 5u)
#undef TFR8
#undef INJ8
}

// uniform [0,1): (bits>>9)|0x3f800000 -> [1,2) -> -1
__device__ inline float u01(uint32_t bits) {
  return __uint_as_float((bits >> 9) | 0x3f800000u) - 1.0f;
}

// E = -log(uniform(tiny,1)); fl((-L)*w) == -fl(L*w) (IEEE sign symmetry), so
// E-then-multiply preserves the original fused -log(v)*winv argmin bit-for-bit.
__device__ inline float egen(uint32_t k0, uint32_t k1, uint32_t ctr) {
  const float TINY = 1.17549435e-38f;
  uint32_t bits = tf_bits(k0, k1, ctr);
  float v = fmaxf(u01(bits), TINY);
  return -__logf(v);
}

// XLA ErfInv32 (Giles) polynomial
__device__ inline float erfinvf_(float x) {
  float w = -log1pf(-x * x);
  float p;
  if (w < 5.0f) {
    w -= 2.5f;
    p = 2.81022636e-08f;
    p = fmaf(p, w, 3.43273939e-07f);
    p = fmaf(p, w, -3.5233877e-06f);
    p = fmaf(p, w, -4.39150654e-06f);
    p = fmaf(p, w, 0.00021858087f);
    p = fmaf(p, w, -0.00125372503f);
    p = fmaf(p, w, -0.00417768164f);
    p = fmaf(p, w, 0.246640727f);
    p = fmaf(p, w, 1.50140941f);
  } else {
    w = sqrtf(w) - 3.0f;
    p = -0.000200214257f;
    p = fmaf(p, w, 0.000100950558f);
    p = fmaf(p, w, 0.00134934322f);
    p = fmaf(p, w, -0.00367342844f);
    p = fmaf(p, w, 0.00573950773f);
    p = fmaf(p, w, -0.0076224613f);
    p = fmaf(p, w, 0.00943887047f);
    p = fmaf(p, w, 1.00167406f);
    p = fmaf(p, w, 2.83297682f);
  }
  return p * x;
}

// Fused: blocks 0..31 -> state = sv@T^T + z@chol(Q) (z regenerated per thread);
//        blocks 32..127 -> Ht (column-major transpose of H, 3 x 8192)
__global__ void __launch_bounds__(256) k_prep(uint32_t k0, uint32_t k1,
                                              const float* __restrict__ sv,
                                              const float* __restrict__ T,
                                              const float* __restrict__ Q,
                                              const float* __restrict__ H,
                                              float* __restrict__ st,
                                              float* __restrict__ ht) {
  int b = blockIdx.x;
  if (b < 32) {
    int i = b * 256 + threadIdx.x;  // particle
    const float lo = -0.99999994f;  // nextafter(-1,0)
    float zz[3];
#pragma unroll
    for (int k = 0; k < 3; k++) {
      uint32_t bits = tf_bits(k0, k1, 3u * (uint32_t)i + (uint32_t)k);
      float v = fmaxf(lo, u01(bits) * 2.0f + lo);  // span fp32(1-lo) == 2.0
      zz[k] = 1.41421356f * erfinvf_(v);           // fp32(sqrt(2))
    }
    float L00 = sqrtf(Q[0]);
    float L10 = Q[3] / L00, L20 = Q[6] / L00;
    float L11 = sqrtf(Q[4] - L10 * L10);
    float L21 = (Q[7] - L20 * L10) / L11;
    float L22 = sqrtf(Q[8] - L20 * L20 - L21 * L21);
    float s0 = sv[i * 3], s1 = sv[i * 3 + 1], s2 = sv[i * 3 + 2];
    float u0 = s0 * T[0] + s1 * T[1] + s2 * T[2];
    float u1 = s0 * T[3] + s1 * T[4] + s2 * T[5];
    float u2 = s0 * T[6] + s1 * T[7] + s2 * T[8];
    st[i * 3]     = u0 + (zz[0] * L00 + zz[1] * L10 + zz[2] * L20);
    st[i * 3 + 1] = u1 + (zz[1] * L11 + zz[2] * L21);
    st[i * 3 + 2] = u2 + (zz[2] * L22);
  } else {
    int t = (b - 32) * 256 + threadIdx.x;  // 0..24575
    int k = t >> 13, j = t & (NP - 1);
    ht[t] = H[j * 3 + k];  // ht[k*8192 + j] = H[j][k]
  }
}

// ---------- k_fused: WAVE-level role mix (proven R7) + 8-way hash chains -----
// Every block identical: wave 0 = one weights row (row = blockIdx), waves 1..3
// = three quarter-rows of E. 1:3 weights:hash wave mix holds on every CU of
// every XCD regardless of dispatch mapping (R5/R6 lesson). RNG inner loop now
// runs 8 interleaved chains (R8 change); E values/locations bit-identical.
__global__ void __launch_bounds__(256) k_fused(uint32_t k0, uint32_t k1,
                                               const float* __restrict__ in,
                                               const float* __restrict__ ht,
                                               const float* __restrict__ st,
                                               float* __restrict__ winv,
                                               float* __restrict__ E) {
  int wave = threadIdx.x >> 6;
  int lane = threadIdx.x & 63;
  if (wave == 0) {
    // ---- weights role: one row per block (proven per-wave body) ----
    int row = blockIdx.x;
    float s0 = st[row * 3], s1 = st[row * 3 + 1], s2 = st[row * 3 + 2];
    const float4* inrow = (const float4*)(in + (size_t)row * NC);
    const float4* h0 = (const float4*)ht;
    const float4* h1 = (const float4*)(ht + NC);
    const float4* h2 = (const float4*)(ht + 2 * NC);
    float acc = 0.0f;
#pragma unroll 4
    for (int it = lane; it < NC / 4; it += 64) {
      float4 x = inrow[it];
      float4 a = h0[it];
      float4 bb = h1[it];
      float4 c = h2[it];
      float d0 = x.x - (a.x * s0 + bb.x * s1 + c.x * s2);
      float d1 = x.y - (a.y * s0 + bb.y * s1 + c.y * s2);
      float d2 = x.z - (a.z * s0 + bb.z * s1 + c.z * s2);
      float d3 = x.w - (a.w * s0 + bb.w * s1 + c.w * s2);
      acc += d0 * d0 + d1 * d1 + d2 * d2 + d3 * d3;
    }
#pragma unroll
    for (int off = 32; off > 0; off >>= 1) acc += __shfl_down(acc, off, 64);
    if (lane == 0) winv[row] = 1.0f / acc;
  } else {
    // ---- RNG role: quarter-sample per wave, 8 values (2 float4) per iter ----
    int gw = blockIdx.x * 3 + (wave - 1);   // 0..24575
    int s = gw >> 2;                        // 0..6143
    int q = gw & 3;                         // quarter within sample
    uint32_t base = (uint32_t)s * (uint32_t)NP;
    float4* erow = (float4*)(E + (size_t)s * NP);
    const float TINY = 1.17549435e-38f;
#pragma unroll 1
    for (int p = 0; p < 8; p += 2) {
      uint32_t i0 = (uint32_t)(q * 2048 + p * 256 + 4 * lane);
      uint32_t x0[8], x1[8];
#pragma unroll
      for (int c = 0; c < 8; c++) {
        uint32_t ctr = base + i0 + (uint32_t)((c & 3) + (c >> 2) * 256);
        x0[c] = k0;            // counter word0 = 0, pre-inject key
        x1[c] = ctr + k1;
      }
      tf20x8(k0, k1, x0, x1);
      float e[8];
#pragma unroll
      for (int c = 0; c < 8; c++) {
        uint32_t bits = x0[c] ^ x1[c];
        float v = fmaxf(u01(bits), TINY);
        e[c] = -__logf(v);
      }
      float4 e4a = {e[0], e[1], e[2], e[3]};
      float4 e4b = {e[4], e[5], e[6], e[7]};
      erow[i0 >> 2] = e4a;             // values i0..i0+3
      erow[(i0 >> 2) + 64] = e4b;      // values i0+256..i0+259
    }
  }
}

// ---------- k_race: E-race (mem-bound) || direct hash-race (VALU-bound) ------
// 3584 blocks, period-7 interleave (3 E-blocks : 4 direct-blocks); verified
// bit-exact R5-R7. Direct path upgraded to 8-way chains (same index set per
// thread, ascending order, strict < -> identical winner).
__global__ void __launch_bounds__(256) k_race(uint32_t k0, uint32_t k1,
                                              const float* __restrict__ E,
                                              const float* __restrict__ winv,
                                              int* __restrict__ idx) {
  int b = blockIdx.x;
  int m = b % 7;
  if (m < 3) {
    // ---- E-path: samples 4e..4e+3, e = 3*(b/7)+m in 0..1535 ----
    int e = (b / 7) * 3 + m;
    int wave = threadIdx.x >> 6;
    int lane = threadIdx.x & 63;
    int s = e * 4 + wave;                   // 0..6143
    const float4* erow = (const float4*)(E + (size_t)s * NP);
    const float4* wv = (const float4*)winv;
    float best = 3.4e38f;
    int bi = 0;
#pragma unroll 4
    for (int it = lane; it < NP / 4; it += 64) {
      float4 ev = erow[it];
      float4 w = wv[it];
      int i = it * 4;
      float r0 = ev.x * w.x;
      float r1 = ev.y * w.y;
      float r2 = ev.z * w.z;
      float r3 = ev.w * w.w;
      if (r0 < best) { best = r0; bi = i; }
      if (r1 < best) { best = r1; bi = i + 1; }
      if (r2 < best) { best = r2; bi = i + 2; }
      if (r3 < best) { best = r3; bi = i + 3; }
    }
#pragma unroll
    for (int off = 32; off > 0; off >>= 1) {
      float ob = __shfl_down(best, off, 64);
      int oi = __shfl_down(bi, off, 64);
      if (ob < best || (ob == best && oi < bi)) { best = ob; bi = oi; }
    }
    if (lane == 0) idx[s] = bi;
  } else {
    // ---- direct path: sample s = 6144 + 4*(b/7) + (m-3), 8-way chains ----
    uint32_t s = (uint32_t)(NS_E + (b / 7) * 4 + (m - 3));   // 6144..8191
    uint32_t base = s * (uint32_t)NP;
    const float TINY = 1.17549435e-38f;
    float best = 3.4e38f;
    int bi = 0;
#pragma unroll 1
    for (int it = 0; it < 4; ++it) {
      uint32_t i0 = (uint32_t)threadIdx.x + (uint32_t)(it * 2048);
      uint32_t x0[8], x1[8];
#pragma unroll
      for (int c = 0; c < 8; c++) {
        x0[c] = k0;
        x1[c] = (base + i0 + (uint32_t)(c * 256)) + k1;
      }
      tf20x8(k0, k1, x0, x1);
#pragma unroll
      for (int c = 0; c < 8; c++) {
        uint32_t bits = x0[c] ^ x1[c];
        float v = fmaxf(u01(bits), TINY);
        uint32_t i = i0 + (uint32_t)(c * 256);
        float r = -__logf(v) * winv[i];
        if (r < best) { best = r; bi = (int)i; }  // ascending i, strict <
      }
    }
    __shared__ float rv[256];
    __shared__ int ri[256];
    rv[threadIdx.x] = best;
    ri[threadIdx.x] = bi;
    __syncthreads();
    for (int stp = 128; stp > 0; stp >>= 1) {
      if (threadIdx.x < stp) {
        float va = rv[threadIdx.x], vb = rv[threadIdx.x + stp];
        int ia = ri[threadIdx.x], ib = ri[threadIdx.x + stp];
        if (vb < va || (vb == va && ib < ia)) { rv[threadIdx.x] = vb; ri[threadIdx.x] = ib; }
      }
      __syncthreads();
    }
    if (threadIdx.x == 0) idx[s] = ri[0];
  }
}

// out = mean over s of state[idx[s]]
__global__ void __launch_bounds__(1024) k_mean(const float* __restrict__ st,
                                               const int* __restrict__ idx,
                                               float* __restrict__ out) {
  double a0 = 0, a1 = 0, a2 = 0;
  for (int s = threadIdx.x; s < NP; s += 1024) {
    int j = idx[s];
    a0 += st[j * 3];
    a1 += st[j * 3 + 1];
    a2 += st[j * 3 + 2];
  }
  __shared__ double r0[1024], r1[1024], r2[1024];
  r0[threadIdx.x] = a0; r1[threadIdx.x] = a1; r2[threadIdx.x] = a2;
  __syncthreads();
  for (int s = 512; s > 0; s >>= 1) {
    if (threadIdx.x < s) {
      r0[threadIdx.x] += r0[threadIdx.x + s];
      r1[threadIdx.x] += r1[threadIdx.x + s];
      r2[threadIdx.x] += r2[threadIdx.x + s];
    }
    __syncthreads();
  }
  if (threadIdx.x == 0) {
    out[0] = (float)(r0[0] / NP);
    out[1] = (float)(r1[0] / NP);
    out[2] = (float)(r2[0] / NP);
  }
}

// ---------------- fallback path (ws too small): original kernels --------------
__global__ void __launch_bounds__(256) k_weights(const float* __restrict__ in,
                                                 const float* __restrict__ ht,
                                                 const float* __restrict__ st,
                                                 float* __restrict__ winv) {
  int wave = threadIdx.x >> 6;
  int lane = threadIdx.x & 63;
  int row = blockIdx.x * 4 + wave;
  float s0 = st[row * 3], s1 = st[row * 3 + 1], s2 = st[row * 3 + 2];
  const float4* inrow = (const float4*)(in + (size_t)row * NC);
  const float4* h0 = (const float4*)ht;
  const float4* h1 = (const float4*)(ht + NC);
  const float4* h2 = (const float4*)(ht + 2 * NC);
  float acc = 0.0f;
#pragma unroll 4
  for (int it = lane; it < NC / 4; it += 64) {
    float4 x = inrow[it];
    float4 a = h0[it];
    float4 b = h1[it];
    float4 c = h2[it];
    float d0 = x.x - (a.x * s0 + b.x * s1 + c.x * s2);
    float d1 = x.y - (a.y * s0 + b.y * s1 + c.y * s2);
    float d2 = x.z - (a.z * s0 + b.z * s1 + c.z * s2);
    float d3 = x.w - (a.w * s0 + b.w * s1 + c.w * s2);
    acc += d0 * d0 + d1 * d1 + d2 * d2 + d3 * d3;
  }
#pragma unroll
  for (int off = 32; off > 0; off >>= 1) acc += __shfl_down(acc, off, 64);
  if (lane == 0) winv[row] = 1.0f / acc;
}

__global__ void __launch_bounds__(256) k_resample(uint32_t k0, uint32_t k1,
                                                  const float* __restrict__ winv,
                                                  int* __restrict__ idx) {
  uint32_t s = blockIdx.x;
  uint32_t base = s * (uint32_t)NP;
  const float TINY = 1.17549435e-38f;
  float best = 3.4e38f;
  int bi = 0;
#pragma unroll 4
  for (uint32_t i = threadIdx.x; i < NP; i += 256) {
    uint32_t bits = tf_bits(k0, k1, base + i);
    float v = fmaxf(u01(bits), TINY);
    float r = -__logf(v) * winv[i];
    if (r < best) { best = r; bi = (int)i; }
  }
  __shared__ float rv[256];
  __shared__ int ri[256];
  rv[threadIdx.x] = best;
  ri[threadIdx.x] = bi;
  __syncthreads();
  for (int stp = 128; stp > 0; stp >>= 1) {
    if (threadIdx.x < stp) {
      float va = rv[threadIdx.x], vb = rv[threadIdx.x + stp];
      int ia = ri[threadIdx.x], ib = ri[threadIdx.x + stp];
      if (vb < va || (vb == va && ib < ia)) { rv[threadIdx.x] = vb; ri[threadIdx.x] = ib; }
    }
    __syncthreads();
  }
  if (threadIdx.x == 0) idx[s] = ri[0];
}

extern "C" void kernel_launch(void* const* d_in, const int* in_sizes, int n_in,
                              void* d_out, int out_size, void* d_ws, size_t ws_size,
                              hipStream_t stream) {
  const float* in = (const float*)d_in[0];   // (1, C, P)
  const float* sv = (const float*)d_in[1];   // (P, 3)
  const float* T  = (const float*)d_in[2];   // (3, 3)
  const float* Q  = (const float*)d_in[3];   // (3, 3)
  const float* H  = (const float*)d_in[4];   // (C, 3)
  float* out = (float*)d_out;                // (3,)

  // partitionable split(key(42)): subkey j = threefry(key, (0, j)) both outputs
  uint32_t nk0, nk1, ck0, ck1;
  threefry2x32(0u, 42u, 0u, 0u, nk0, nk1);  // k_noise
  threefry2x32(0u, 42u, 0u, 1u, ck0, ck1);  // k_cat

  const size_t eFloats = (size_t)NP * (size_t)NP;        // full 8192-row layout
  const size_t tailBytes = (24576 + 24576 + NP + NP) * 4; // st+ht+winv+idx
  const bool fused = ws_size >= eFloats * 4 + tailBytes;

  if (fused) {
    float* E    = (float*)d_ws;          // 256 MB (only rows 0..6143 used)
    float* st   = E + eFloats;           // 24576 f
    float* ht   = st + 24576;            // 24576 f
    float* winv = ht + 24576;            // 8192 f
    int*   idx  = (int*)(winv + NP);     // 8192 i

    hipLaunchKernelGGL(k_prep, dim3(128), dim3(256), 0, stream, nk0, nk1, sv, T, Q, H, st, ht);
    hipLaunchKernelGGL(k_fused, dim3(8192), dim3(256), 0, stream, ck0, ck1, in, ht, st, winv, E);
    hipLaunchKernelGGL(k_race, dim3(3584), dim3(256), 0, stream, ck0, ck1, E, winv, idx);
    hipLaunchKernelGGL(k_mean, dim3(1), dim3(1024), 0, stream, st, idx, out);
  } else {
    float* st   = (float*)d_ws;          // 24576 f
    float* ht   = st + 24576;            // 24576 f
    float* winv = ht + 24576;            // 8192 f
    int*   idx  = (int*)(winv + NP);     // 8192 i

    hipLaunchKernelGGL(k_prep, dim3(128), dim3(256), 0, stream, nk0, nk1, sv, T, Q, H, st, ht);
    hipLaunchKernelGGL(k_weights, dim3(NP / 4), dim3(256), 0, stream, in, ht, st, winv);
    hipLaunchKernelGGL(k_resample, dim3(NP), dim3(256), 0, stream, ck0, ck1, winv, idx);
    hipLaunchKernelGGL(k_mean, dim3(1), dim3(1024), 0, stream, st, idx, out);
  }
}